// Round 3
// baseline (49.014 us; speedup 1.0000x reference)
//
#include <hip/hip_runtime.h>
#include <hip/hip_bf16.h>

// out[b,o] = sum_{i,n} T_n(x[b,i]) * w[o,i,n]
// GEMM view: M=B=65536, N=O=32, K=I*8=2048. MFMA v_mfma_f32_32x32x16_bf16,
// K-chunk 16 = one i-pair (kc2 = 0..127).
// Block: 256 thr = 4 waves; waves split M (32 rows each, block M=128).
// K processed in 4 chunks of 32 kc2; x chunk [128][32 f2] in 32 KB LDS,
// reg-staged with issue-early/write-late overlap (T14), f2 XOR-swizzled.

typedef __attribute__((ext_vector_type(8)))  short bf16x8;
typedef __attribute__((ext_vector_type(16))) float f32x16;

__device__ __forceinline__ short f2b(float f) {
    __hip_bfloat16 h = __float2bfloat16(f);
    short s;
    __builtin_memcpy(&s, &h, sizeof(s));
    return s;
}

// Pack w [32][256][8] fp32 -> wB[kc2][lane][jj] bf16 in B-fragment order:
//   o = lane&31, g = lane>>5, i = 2*kc2 + (jj>>2), n = 4*g + (jj&3)
// (HW-verified: round-2 kernel with this layout passed, absmax 1.95e-3)
__global__ __launch_bounds__(256) void prep_w_kernel(const float* __restrict__ w,
                                                     short* __restrict__ wB) {
    int idx = blockIdx.x * 256 + threadIdx.x;     // 0..65535
    int kc2 = idx >> 9;
    int l   = (idx >> 3) & 63;
    int jj  = idx & 7;
    int o = l & 31, g = l >> 5;
    int i = 2 * kc2 + (jj >> 2);
    int n = 4 * g + (jj & 3);
    wB[idx] = f2b(w[(o * 256 + i) * 8 + n]);
}

__global__ __launch_bounds__(256) void cheb_mm_kernel(const float* __restrict__ x,
                                                      const short* __restrict__ wB,
                                                      float* __restrict__ out) {
    __shared__ float smem[8192];                  // 32 KB: [128 rows][32 f2], swizzled
    const int tid = threadIdx.x;
    const int wv  = tid >> 6;
    const int l   = tid & 63;
    const int g   = l >> 5;                       // n-half selector
    const int r0  = l & 31;                       // row-in-wave-tile / o column
    const long long rowB = (long long)blockIdx.x * 128;

    const float4* xg4 = (const float4*)x;         // 64 float4 per row
    float2* s2 = (float2*)smem;

    float4 stg[8];                                // staged chunk (128 B/thread)

    auto LOAD = [&](int c) {                      // coalesced global -> regs
        #pragma unroll
        for (int q = 0; q < 8; ++q) {
            int S = q * 256 + tid;                // 16B-slot id in chunk
            int row = S >> 4, f4 = S & 15;
            stg[q] = xg4[(rowB + row) * 64 + c * 16 + f4];
        }
    };
    auto WRITE = [&]() {                          // regs -> LDS, f2 XOR swizzle
        #pragma unroll
        for (int q = 0; q < 8; ++q) {
            int S = q * 256 + tid;
            int row = S >> 4, f4 = S & 15;
            int p0 = (2 * f4)     ^ (row & 31);
            int p1 = (2 * f4 + 1) ^ (row & 31);
            s2[row * 32 + p0] = make_float2(stg[q].x, stg[q].y);
            s2[row * 32 + p1] = make_float2(stg[q].z, stg[q].w);
        }
    };

    LOAD(0); WRITE(); __syncthreads();

    f32x16 acc{};
    const bf16x8* wBv = (const bf16x8*)wB;
    const float2* srow = s2 + (wv * 32 + r0) * 32;   // this lane's row base

    for (int c = 0; c < 4; ++c) {
        if (c < 3) LOAD(c + 1);                   // prefetch next chunk (in flight)
        #pragma unroll 8
        for (int t = 0; t < 32; ++t) {
            const int kc2 = c * 32 + t;
            const bf16x8 bfrag = wBv[kc2 * 64 + l];   // L1/L2-resident
            const float2 xv = srow[t ^ r0];           // swizzled, ~conflict-free
            const float xa = xv.x, xb = xv.y;
            const float x2a = xa + xa, x2b = xb + xb;
            const float a2 = x2a * xa - 1.f;
            const float a3 = x2a * a2 - xa;
            const float a4 = x2a * a3 - a2;
            const float a5 = x2a * a4 - a3;
            const float b2 = x2b * xb - 1.f;
            const float b3 = x2b * b2 - xb;
            const float b4 = x2b * b3 - b2;
            const float b5 = x2b * b4 - b3;
            const float ua0 = g ? a4 : 1.f;
            const float ua1 = g ? a5 : xa;
            const float ua2 = x2a * ua1 - ua0;    // T6 or T2
            const float ua3 = x2a * ua2 - ua1;    // T7 or T3
            const float ub0 = g ? b4 : 1.f;
            const float ub1 = g ? b5 : xb;
            const float ub2 = x2b * ub1 - ub0;
            const float ub3 = x2b * ub2 - ub1;
            bf16x8 afrag;
            afrag[0] = f2b(ua0); afrag[1] = f2b(ua1);
            afrag[2] = f2b(ua2); afrag[3] = f2b(ua3);
            afrag[4] = f2b(ub0); afrag[5] = f2b(ub1);
            afrag[6] = f2b(ub2); afrag[7] = f2b(ub3);
            acc = __builtin_amdgcn_mfma_f32_32x32x16_bf16(afrag, bfrag, acc, 0, 0, 0);
        }
        __syncthreads();                          // all waves done reading chunk c
        if (c < 3) { WRITE(); __syncthreads(); }  // land prefetched chunk
    }

    // direct store: C/D layout col=lane&31, row=(r&3)+8*(r>>2)+4*g (HW-verified)
    float* op = out + (rowB + wv * 32) * 32 + r0;
    #pragma unroll
    for (int r = 0; r < 16; ++r) {
        const int rloc = (r & 3) + 8 * (r >> 2) + 4 * g;
        op[rloc * 32] = acc[r];
    }
}

extern "C" void kernel_launch(void* const* d_in, const int* in_sizes, int n_in,
                              void* d_out, int out_size, void* d_ws, size_t ws_size,
                              hipStream_t stream) {
    const float* x = (const float*)d_in[0];   // [65536, 256] fp32
    const float* w = (const float*)d_in[1];   // [32, 256, 8] fp32
    float* out = (float*)d_out;               // [65536, 32] fp32
    short* wB = (short*)d_ws;                 // 128 KB bf16 packed weights

    prep_w_kernel<<<256, 256, 0, stream>>>(w, wB);
    cheb_mm_kernel<<<512, 256, 0, stream>>>(x, wB, out);
}

// Round 4
// 33.759 us; speedup vs baseline: 1.4519x; 1.4519x over previous
//
#include <hip/hip_runtime.h>
#include <hip/hip_bf16.h>

// out[b,o] = sum_{i,n} T_n(x[b,i]) * w[o,i,n]
// GEMM view: M=B=65536, N=O=32, K=I*8=2048. MFMA v_mfma_f32_32x32x16_bf16.
// Round-4 structure: block = 256 thr = 4 waves owns ONE 32-row tile.
//   - stage x[32 rows][256 f] = contiguous 32 KB -> LDS (swizzled), 1 barrier
//   - waves split K by 4 (32 kc2 each), 32 MFMA iters, no barriers inside
//   - partials -> LDS, 1 barrier, 4-way reduce, coalesced store
// 32 KB LDS -> 5 blocks/CU = 20 waves/CU; grid 2048 blocks (8 per CU queued).

typedef __attribute__((ext_vector_type(8)))  short bf16x8;
typedef __attribute__((ext_vector_type(16))) float f32x16;
typedef __attribute__((ext_vector_type(4)))  float f32x4;

__device__ __forceinline__ short f2b(float f) {
    __hip_bfloat16 h = __float2bfloat16(f);
    short s;
    __builtin_memcpy(&s, &h, sizeof(s));
    return s;
}

// Pack w [32][256][8] fp32 -> wB[kc2][lane][jj] bf16 in B-fragment order:
//   o = lane&31, g = lane>>5, i = 2*kc2 + (jj>>2), n = 4*g + (jj&3)
// (HW-verified: rounds 2-3 passed with this layout, absmax 1.95e-3)
__global__ __launch_bounds__(256) void prep_w_kernel(const float* __restrict__ w,
                                                     short* __restrict__ wB) {
    int idx = blockIdx.x * 256 + threadIdx.x;     // 0..65535
    int kc2 = idx >> 9;
    int l   = (idx >> 3) & 63;
    int jj  = idx & 7;
    int o = l & 31, g = l >> 5;
    int i = 2 * kc2 + (jj >> 2);
    int n = 4 * g + (jj & 3);
    wB[idx] = f2b(w[(o * 256 + i) * 8 + n]);
}

__global__ __launch_bounds__(256, 5) void cheb_mm_kernel(const float* __restrict__ x,
                                                         const short* __restrict__ wB,
                                                         float* __restrict__ out) {
    __shared__ float smem[8192];                  // 32 KB: x-tile, then partials
    const int tid = threadIdx.x;
    const int wv  = tid >> 6;                     // K-quarter selector
    const int l   = tid & 63;
    const int g   = l >> 5;                       // n-half selector
    const int r0  = l & 31;                       // batch row in tile / o column
    const long long rowB = (long long)blockIdx.x * 32;

    // ---- one-shot stage: 32 KB contiguous global -> LDS, XOR-swizzled f2 ----
    {
        const float4* xg4 = (const float4*)(x + rowB * 256);
        float4 stg[8];
        #pragma unroll
        for (int q = 0; q < 8; ++q)
            stg[q] = xg4[q * 256 + tid];          // fully coalesced, all in flight
        float2* s2 = (float2*)smem;
        #pragma unroll
        for (int q = 0; q < 8; ++q) {
            int slot = q * 256 + tid;             // 16B-slot id in tile
            int row = slot >> 6, f4 = slot & 63;  // 64 slots per 1KB row
            int p0 = 2 * f4, p1 = 2 * f4 + 1;     // f2 indices 0..127
            int d0 = (p0 & ~31) + ((p0 & 31) ^ (row & 31));
            int d1 = (p1 & ~31) + ((p1 & 31) ^ (row & 31));
            s2[row * 128 + d0] = make_float2(stg[q].x, stg[q].y);
            s2[row * 128 + d1] = make_float2(stg[q].z, stg[q].w);
        }
    }
    __syncthreads();

    // ---- compute: wave wv handles kc2 = wv*32 .. wv*32+31, no barriers ----
    f32x16 acc{};
    const bf16x8* wBv = (const bf16x8*)wB;
    const float2* srow = (const float2*)smem + r0 * 128 + wv * 32;

    #pragma unroll 8
    for (int t = 0; t < 32; ++t) {
        const bf16x8 bfrag = wBv[(wv * 32 + t) * 64 + l];  // L1/L2-resident
        const float2 xv = srow[t ^ r0];                    // swizzled, ~2-way max
        const float xa = xv.x, xb = xv.y;
        const float x2a = xa + xa, x2b = xb + xb;
        const float a2 = x2a * xa - 1.f;
        const float a3 = x2a * a2 - xa;
        const float a4 = x2a * a3 - a2;
        const float a5 = x2a * a4 - a3;
        const float b2 = x2b * xb - 1.f;
        const float b3 = x2b * b2 - xb;
        const float b4 = x2b * b3 - b2;
        const float b5 = x2b * b4 - b3;
        const float ua0 = g ? a4 : 1.f;
        const float ua1 = g ? a5 : xa;
        const float ua2 = x2a * ua1 - ua0;        // T6 or T2
        const float ua3 = x2a * ua2 - ua1;        // T7 or T3
        const float ub0 = g ? b4 : 1.f;
        const float ub1 = g ? b5 : xb;
        const float ub2 = x2b * ub1 - ub0;
        const float ub3 = x2b * ub2 - ub1;
        bf16x8 afrag;
        afrag[0] = f2b(ua0); afrag[1] = f2b(ua1);
        afrag[2] = f2b(ua2); afrag[3] = f2b(ua3);
        afrag[4] = f2b(ub0); afrag[5] = f2b(ub1);
        afrag[6] = f2b(ub2); afrag[7] = f2b(ub3);
        acc = __builtin_amdgcn_mfma_f32_32x32x16_bf16(afrag, bfrag, acc, 0, 0, 0);
    }

    __syncthreads();                              // all waves done reading x
    // partials[wv][batchrow][o]: C/D col=lane&31(=o), row=(r&3)+8*(r>>2)+4*g
    #pragma unroll
    for (int r = 0; r < 16; ++r) {
        const int rloc = (r & 3) + 8 * (r >> 2) + 4 * g;
        smem[wv * 1024 + rloc * 32 + r0] = acc[r];
    }
    __syncthreads();

    // 4-way reduce + coalesced f32x4 store of out[32][32] tile
    {
        float* op = out + rowB * 32;
        const int f = tid * 4;                    // 1024 floats / 256 thr
        f32x4 v0 = *(const f32x4*)&smem[f];
        f32x4 v1 = *(const f32x4*)&smem[1024 + f];
        f32x4 v2 = *(const f32x4*)&smem[2048 + f];
        f32x4 v3 = *(const f32x4*)&smem[3072 + f];
        f32x4 s = (v0 + v1) + (v2 + v3);
        *(f32x4*)(op + f) = s;
    }
}

extern "C" void kernel_launch(void* const* d_in, const int* in_sizes, int n_in,
                              void* d_out, int out_size, void* d_ws, size_t ws_size,
                              hipStream_t stream) {
    const float* x = (const float*)d_in[0];   // [65536, 256] fp32
    const float* w = (const float*)d_in[1];   // [32, 256, 8] fp32
    float* out = (float*)d_out;               // [65536, 32] fp32
    short* wB = (short*)d_ws;                 // 128 KB bf16 packed weights

    prep_w_kernel<<<256, 256, 0, stream>>>(w, wB);
    cheb_mm_kernel<<<2048, 256, 0, stream>>>(x, wB, out);
}

// Round 6
// 32.237 us; speedup vs baseline: 1.5204x; 1.0472x over previous
//
#include <hip/hip_runtime.h>
#include <hip/hip_bf16.h>

// out[b,o] = sum_{i,n} T_n(x[b,i]) * w[o,i,n]
// GEMM view: M=B=65536, N=O=32, K=I*8=2048. MFMA v_mfma_f32_32x32x16_bf16.
// Round-6: round-4 shape (2048 blocks, 32-row tile, 4 waves K-split, 32KB LDS).
// Inner loop: each lane computes ONE x's T0..T7 chain (g=lane>>5 picks parity),
// packs 4 bf16x2 words, and TWO permlane32_swap (BUILTIN -> hazard-safe) build
// the A-frag for both halves with zero cndmask. Depth-4 bfrag + depth-2 x
// register prefetch hide L2/LDS latency. Fallback (#if no builtin): round-4
// proven dual-chain + cndmask body.

typedef __attribute__((ext_vector_type(8)))  short bf16x8;
typedef __attribute__((ext_vector_type(16))) float f32x16;
typedef __attribute__((ext_vector_type(4)))  float f32x4;

__device__ __forceinline__ short f2b(float f) {
    __hip_bfloat16 h = __float2bfloat16(f);
    short s;
    __builtin_memcpy(&s, &h, sizeof(s));
    return s;
}

__device__ __forceinline__ unsigned pkbf(float lo, float hi) {
    __hip_bfloat162 h2 = __float22bfloat162_rn(make_float2(lo, hi));
    unsigned u;
    __builtin_memcpy(&u, &h2, 4);
    return u;
}

// Pack w [32][256][8] fp32 -> wB[kc2][lane][jj] bf16 in B-fragment order:
//   o = lane&31, g = lane>>5, i = 2*kc2 + (jj>>2), n = 4*g + (jj&3)
// (HW-verified: rounds 2-4 passed with this layout, absmax 1.95e-3)
__global__ __launch_bounds__(256) void prep_w_kernel(const float* __restrict__ w,
                                                     short* __restrict__ wB) {
    int idx = blockIdx.x * 256 + threadIdx.x;     // 0..65535
    int kc2 = idx >> 9;
    int l   = (idx >> 3) & 63;
    int jj  = idx & 7;
    int o = l & 31, g = l >> 5;
    int i = 2 * kc2 + (jj >> 2);
    int n = 4 * g + (jj & 3);
    wB[idx] = f2b(w[(o * 256 + i) * 8 + n]);
}

__global__ __launch_bounds__(256, 5) void cheb_mm_kernel(const float* __restrict__ x,
                                                         const short* __restrict__ wB,
                                                         float* __restrict__ out) {
    __shared__ float smem[8192];                  // 32 KB: x-tile, then partials
    const int tid = threadIdx.x;
    const int wv  = tid >> 6;                     // K-quarter selector
    const int l   = tid & 63;
    const int g   = l >> 5;                       // i-parity this lane computes
    const int r0  = l & 31;                       // batch row in tile / o column
    const long long rowB = (long long)blockIdx.x * 32;

    // ---- one-shot stage: 32 KB contiguous global -> LDS, XOR-swizzled f2 ----
    // (identical to rounds 4/5 — proven)
    {
        const float4* xg4 = (const float4*)(x + rowB * 256);
        float4 stg[8];
        #pragma unroll
        for (int q = 0; q < 8; ++q)
            stg[q] = xg4[q * 256 + tid];          // fully coalesced, all in flight
        float2* s2 = (float2*)smem;
        #pragma unroll
        for (int q = 0; q < 8; ++q) {
            int slot = q * 256 + tid;             // 16B-slot id in tile
            int row = slot >> 6, f4 = slot & 63;  // 64 slots per 1KB row
            int p0 = 2 * f4, p1 = 2 * f4 + 1;     // f2 indices 0..127
            int d0 = (p0 & ~31) + ((p0 & 31) ^ (row & 31));
            int d1 = (p1 & ~31) + ((p1 & 31) ^ (row & 31));
            s2[row * 128 + d0] = make_float2(stg[q].x, stg[q].y);
            s2[row * 128 + d1] = make_float2(stg[q].z, stg[q].w);
        }
    }
    __syncthreads();

    // ---- compute: wave wv handles kc2 = wv*32 .. wv*32+31, no barriers ----
    f32x16 accA{}, accB{};
    const bf16x8* wq = (const bf16x8*)wB + wv * 2048 + l;   // element t: wq[t*64]
    const float* sf = smem;
    const int xbase = r0 * 256 + wv * 64 + g;     // + ((t^r0)<<1) per iter

#if __has_builtin(__builtin_amdgcn_permlane32_swap)
    // register-prefetch pipelines (statically indexed under full unroll)
    bf16x8 bfc[4];
    float  xc[2];
    #pragma unroll
    for (int p = 0; p < 4; ++p) bfc[p] = wq[p * 64];
    xc[0] = sf[xbase + ((0 ^ r0) << 1)];
    xc[1] = sf[xbase + ((1 ^ r0) << 1)];

    #pragma unroll
    for (int t = 0; t < 32; ++t) {
        const bf16x8 bfrag = bfc[t & 3];
        const float  xv    = xc[t & 1];
        if (t + 4 < 32) bfc[t & 3] = wq[(t + 4) * 64];
        if (t + 2 < 32) xc[t & 1] = sf[xbase + (((t + 2) ^ r0) << 1)];

        const float x2 = xv + xv;
        const float T2 = fmaf(x2, xv, -1.f);
        const float T3 = fmaf(x2, T2, -xv);
        const float T4 = fmaf(x2, T3, -T2);
        const float T5 = fmaf(x2, T4, -T3);
        const float T6 = fmaf(x2, T5, -T4);
        const float T7 = fmaf(x2, T6, -T5);
        unsigned R0 = pkbf(1.f, xv);              // T0,T1 of own x
        unsigned R1 = pkbf(T2, T3);
        unsigned R2 = pkbf(T4, T5);
        unsigned R3 = pkbf(T6, T7);
        // dst-hi <-> src-lo swap; builtin returns {new_dst, new_src}.
        // After both swaps every lane holds the round-4-identical A-frag:
        //   g=0: [T0a..T3a | T0b..T3b], g=1: [T4a..T7a | T4b..T7b]
        auto r02 = __builtin_amdgcn_permlane32_swap(R0, R2, false, false);
        auto r13 = __builtin_amdgcn_permlane32_swap(R1, R3, false, false);
        union { unsigned u[4]; bf16x8 v; } af;
        af.u[0] = r02[0]; af.u[1] = r13[0];
        af.u[2] = r02[1]; af.u[3] = r13[1];
        if (t & 1)
            accB = __builtin_amdgcn_mfma_f32_32x32x16_bf16(af.v, bfrag, accB, 0, 0, 0);
        else
            accA = __builtin_amdgcn_mfma_f32_32x32x16_bf16(af.v, bfrag, accA, 0, 0, 0);
    }
#else
    // fallback: round-4 proven body (dual chain + cndmask), f2 reads
    const float2* srow = (const float2*)smem + r0 * 128 + wv * 32;
    #pragma unroll 8
    for (int t = 0; t < 32; ++t) {
        const bf16x8 bfrag = wq[t * 64];
        const float2 xv = srow[t ^ r0];
        const float xa = xv.x, xb = xv.y;
        const float x2a = xa + xa, x2b = xb + xb;
        const float a2 = x2a * xa - 1.f;
        const float a3 = x2a * a2 - xa;
        const float a4 = x2a * a3 - a2;
        const float a5 = x2a * a4 - a3;
        const float b2 = x2b * xb - 1.f;
        const float b3 = x2b * b2 - xb;
        const float b4 = x2b * b3 - b2;
        const float b5 = x2b * b4 - b3;
        const float ua0 = g ? a4 : 1.f;
        const float ua1 = g ? a5 : xa;
        const float ua2 = x2a * ua1 - ua0;
        const float ua3 = x2a * ua2 - ua1;
        const float ub0 = g ? b4 : 1.f;
        const float ub1 = g ? b5 : xb;
        const float ub2 = x2b * ub1 - ub0;
        const float ub3 = x2b * ub2 - ub1;
        bf16x8 afrag;
        afrag[0] = f2b(ua0); afrag[1] = f2b(ua1);
        afrag[2] = f2b(ua2); afrag[3] = f2b(ua3);
        afrag[4] = f2b(ub0); afrag[5] = f2b(ub1);
        afrag[6] = f2b(ub2); afrag[7] = f2b(ub3);
        if (t & 1)
            accB = __builtin_amdgcn_mfma_f32_32x32x16_bf16(afrag, bfrag, accB, 0, 0, 0);
        else
            accA = __builtin_amdgcn_mfma_f32_32x32x16_bf16(afrag, bfrag, accA, 0, 0, 0);
    }
#endif
    const f32x16 acc = accA + accB;

    __syncthreads();                              // all waves done reading x
    // partials[wv][batchrow][o]: C/D col=lane&31(=o), row=(r&3)+8*(r>>2)+4*g
    #pragma unroll
    for (int r = 0; r < 16; ++r) {
        const int rloc = (r & 3) + 8 * (r >> 2) + 4 * g;
        smem[wv * 1024 + rloc * 32 + r0] = acc[r];
    }
    __syncthreads();

    // 4-way reduce + coalesced f32x4 store of out[32][32] tile
    {
        float* op = out + rowB * 32;
        const int f = tid * 4;                    // 1024 floats / 256 thr
        f32x4 v0 = *(const f32x4*)&smem[f];
        f32x4 v1 = *(const f32x4*)&smem[1024 + f];
        f32x4 v2 = *(const f32x4*)&smem[2048 + f];
        f32x4 v3 = *(const f32x4*)&smem[3072 + f];
        f32x4 s = (v0 + v1) + (v2 + v3);
        *(f32x4*)(op + f) = s;
    }
}

extern "C" void kernel_launch(void* const* d_in, const int* in_sizes, int n_in,
                              void* d_out, int out_size, void* d_ws, size_t ws_size,
                              hipStream_t stream) {
    const float* x = (const float*)d_in[0];   // [65536, 256] fp32
    const float* w = (const float*)d_in[1];   // [32, 256, 8] fp32
    float* out = (float*)d_out;               // [65536, 32] fp32
    short* wB = (short*)d_ws;                 // 128 KB bf16 packed weights

    prep_w_kernel<<<256, 256, 0, stream>>>(w, wB);
    cheb_mm_kernel<<<2048, 256, 0, stream>>>(x, wB, out);
}